// Round 1
// baseline (538.997 us; speedup 1.0000x reference)
//
#include <hip/hip_runtime.h>

#define SINGLE_DIM 256
#define PAIR_DIM   64
#define MAX_REL    32
#define LN_EPS     1e-5f
#define N_FIXED    1024
#define ST_STRIDE  68   // 64 + 4 pad floats: odd float4 stride -> <=2-way LDS banks

typedef float vfloat4 __attribute__((ext_vector_type(4)));

// ---------------------------------------------------------------------------
// Kernel A: proj[row][c], c in [0,128): c<64 -> s@W_i + bias, c>=64 -> s@W_j
// One block = 2 rows x 128 cols = 256 threads. Each wave additionally reduces
// its 64 lanes (= one full 64-channel row-half) to (sum, sum_sq) row stats.
// ---------------------------------------------------------------------------
__global__ __launch_bounds__(256) void proj_kernel(
    const float* __restrict__ s,        // (B*N, 256)
    const float* __restrict__ W,        // (512, 64) = [W_i; W_j]
    const float* __restrict__ bias,     // (64,)
    float* __restrict__ proj,           // (B*N, 128) = [pi+b | pj]
    float* __restrict__ rowstats)       // (B*N, 4) = sum_i, ssq_i, sum_j, ssq_j (or null)
{
    __shared__ float lds[2][SINGLE_DIM];
    const int row0 = blockIdx.x * 2;
    const int t = threadIdx.x;

    ((float2*)(&lds[0][0]))[t] = ((const float2*)(s + (size_t)row0 * SINGLE_DIM))[t];
    __syncthreads();

    const int row  = t >> 7;         // 0..1 (wave-uniform)
    const int c    = t & 127;        // 0..127
    const int half = c >> 6;         // wave-uniform
    const int p    = c & 63;

    const float* wcol = W + half * (SINGLE_DIM * PAIR_DIM) + p;
    const float* srow = lds[row];

    float acc = (half == 0) ? bias[p] : 0.f;
    #pragma unroll 8
    for (int d = 0; d < SINGLE_DIM; ++d)
        acc += srow[d] * wcol[d * PAIR_DIM];

    proj[(size_t)(row0 + row) * 128 + c] = acc;

    if (rowstats) {
        // full-wave (64-lane) reduce of acc and acc^2 -> per-row-half stats
        float sv = acc, qv = acc * acc;
        #pragma unroll
        for (int mask = 1; mask < 64; mask <<= 1) {
            sv += __shfl_xor(sv, mask, 64);
            qv += __shfl_xor(qv, mask, 64);
        }
        if ((t & 63) == 0)
            *(float2*)(rowstats + (size_t)(row0 + row) * 4 + half * 2) =
                make_float2(sv, qv);
    }
}

// ---------------------------------------------------------------------------
// Kernel S: per-pair LN statistics. dot_ij = <pi', pj> via fp32 LDS-tiled
// GEMM (64x64 tile, K=64). mean = (sum_i+sum_j)/64;
// var = (ssq_i+ssq_j+2*dot)/64 - mean^2; writes (mean, rstd) per (bi, j).
// Grid: B * 16 * 16 = 512 blocks, 256 threads (16x16, 4x4 outputs each).
// ---------------------------------------------------------------------------
__global__ __launch_bounds__(256) void stats_kernel(
    const float* __restrict__ proj,      // (B*N, 128)
    const float* __restrict__ rowstats,  // (B*N, 4)
    float2* __restrict__ M)              // (B*N, N): mean, rstd
{
    __shared__ __align__(16) float A [64 * ST_STRIDE];
    __shared__ __align__(16) float Bt[64 * ST_STRIDE];

    const int t   = threadIdx.x;
    const int bid = blockIdx.x;
    const int b   = bid >> 8;
    const int it  = (bid >> 4) & 15;
    const int jt  = bid & 15;
    const int i0  = b * N_FIXED + it * 64;   // global proj row of first i
    const int j0  = b * N_FIXED + jt * 64;   // global proj row of first j

    // stage both 64x64 tiles (coalesced 256B runs; LDS banks <=2-way via pad)
    #pragma unroll
    for (int x = 0; x < 4; ++x) {
        const int idx = t + 256 * x;          // 0..1023
        const int r   = idx >> 4;
        const int c4  = idx & 15;
        float4 va = *(const float4*)(proj + (size_t)(i0 + r) * 128 + c4 * 4);
        float4 vb = *(const float4*)(proj + (size_t)(j0 + r) * 128 + 64 + c4 * 4);
        *(float4*)(A  + r * ST_STRIDE + c4 * 4) = va;
        *(float4*)(Bt + r * ST_STRIDE + c4 * 4) = vb;
    }
    __syncthreads();

    const int tx = t & 15, ty = t >> 4;
    // i rows: ty*4 + r ; j cols: tx + 16*c (stride-16 -> conflict-free + coalesced M store)
    float acc[4][4] = {};
    #pragma unroll
    for (int kk = 0; kk < 16; ++kk) {
        float4 a[4], bb[4];
        #pragma unroll
        for (int r = 0; r < 4; ++r)
            a[r] = *(const float4*)(A + (ty * 4 + r) * ST_STRIDE + kk * 4);
        #pragma unroll
        for (int c = 0; c < 4; ++c)
            bb[c] = *(const float4*)(Bt + (tx + 16 * c) * ST_STRIDE + kk * 4);
        #pragma unroll
        for (int r = 0; r < 4; ++r)
            #pragma unroll
            for (int c = 0; c < 4; ++c)
                acc[r][c] += a[r].x * bb[c].x + a[r].y * bb[c].y
                           + a[r].z * bb[c].z + a[r].w * bb[c].w;
    }

    float2 si[4], sj[4];
    #pragma unroll
    for (int r = 0; r < 4; ++r)
        si[r] = *(const float2*)(rowstats + (size_t)(i0 + ty * 4 + r) * 4);
    #pragma unroll
    for (int c = 0; c < 4; ++c)
        sj[c] = *(const float2*)(rowstats + (size_t)(j0 + tx + 16 * c) * 4 + 2);

    #pragma unroll
    for (int r = 0; r < 4; ++r) {
        const size_t mrow = (size_t)(i0 + ty * 4 + r) * N_FIXED;
        #pragma unroll
        for (int c = 0; c < 4; ++c) {
            const float mean = (si[r].x + sj[c].x) * (1.f / PAIR_DIM);
            const float ex2  = (si[r].y + sj[c].y + 2.f * acc[r][c]) * (1.f / PAIR_DIM);
            const float rstd = rsqrtf(ex2 - mean * mean + LN_EPS);
            M[mrow + jt * 64 + tx + 16 * c] = make_float2(mean, rstd);
        }
    }
}

// ---------------------------------------------------------------------------
// Kernel B (fast): pure streaming epilogue. No reduce, no DS ops.
// out = relu(fma(pi+pj, gamma*rstd, beta - mean*gamma*rstd)) + embed.
// Same grid/coalescing as the proven kernel: 16-lane group per (bi) x 4 j.
// ---------------------------------------------------------------------------
__global__ __launch_bounds__(256) void pair_fast_kernel(
    const float* __restrict__ proj,   // (B*N, 128)
    const float2* __restrict__ M,     // (B*N, N)
    const float* __restrict__ gamma,
    const float* __restrict__ beta,
    const float* __restrict__ embed,  // (65, 64)
    float* __restrict__ out)          // (B, N, N, 64)
{
    const int t  = threadIdx.x;
    const int g  = t >> 4;
    const int p0 = (t & 15) * 4;
    const int bid = blockIdx.x;
    const int bi    = bid >> 4;
    const int jbase = (bid & 15) * 64 + g;
    const int i = bi & (N_FIXED - 1);

    const float4 pi4 = *(const float4*)(proj + (size_t)bi * 128 + p0);
    const float4 g4  = *(const float4*)(gamma + p0);
    const float4 b4  = *(const float4*)(beta + p0);
    const size_t mrow = (size_t)bi * N_FIXED;

    #pragma unroll
    for (int k = 0; k < 4; ++k) {
        const int j = jbase + 16 * k;
        const float4 pj4 = *(const float4*)(proj + mrow * 0 + (size_t)((bi >> 10) * N_FIXED + j) * 128 + 64 + p0);
        const float2 mr  = M[mrow + j];      // broadcast across 16-lane group
        const float mean = mr.x, rstd = mr.y;

        const float Gx = g4.x * rstd, Gy = g4.y * rstd,
                    Gz = g4.z * rstd, Gw = g4.w * rstd;
        const float Bx = fmaf(-mean, Gx, b4.x), By = fmaf(-mean, Gy, b4.y),
                    Bz = fmaf(-mean, Gz, b4.z), Bw = fmaf(-mean, Gw, b4.w);

        int rel = j - i;
        rel = (rel < -MAX_REL) ? -MAX_REL : (rel > MAX_REL ? MAX_REL : rel);
        rel += MAX_REL;
        const float4 e4 = *(const float4*)(embed + rel * PAIR_DIM + p0);

        vfloat4 o;
        o.x = fmaxf(fmaf(pi4.x + pj4.x, Gx, Bx), 0.f) + e4.x;
        o.y = fmaxf(fmaf(pi4.y + pj4.y, Gy, By), 0.f) + e4.y;
        o.z = fmaxf(fmaf(pi4.z + pj4.z, Gz, Bz), 0.f) + e4.z;
        o.w = fmaxf(fmaf(pi4.w + pj4.w, Gw, Bw), 0.f) + e4.w;

        __builtin_nontemporal_store(o,
            (vfloat4*)(out + ((size_t)bi * N_FIXED + j) * PAIR_DIM + p0));
    }
}

// ---------------------------------------------------------------------------
// Kernel B (fallback, proven): in-kernel shuffle-reduce LN. Used when d_ws is
// too small for the (mean,rstd) table.
// ---------------------------------------------------------------------------
__global__ __launch_bounds__(256) void pair_kernel(
    const float* __restrict__ proj,
    const float* __restrict__ gamma,
    const float* __restrict__ beta,
    const float* __restrict__ embed,
    float* __restrict__ out)
{
    const int t  = threadIdx.x;
    const int g  = t >> 4;
    const int p0 = (t & 15) * 4;
    const int bid = blockIdx.x;
    const int bi    = bid >> 4;
    const int jbase = (bid & 15) * 64 + g;
    const int i = bi & (N_FIXED - 1);
    const int b = bi >> 10;

    const float4 pi4 = *(const float4*)(proj + (size_t)bi * 128 + p0);
    const float4 g4  = *(const float4*)(gamma + p0);
    const float4 b4  = *(const float4*)(beta + p0);

    float4 v[4];
    float  s[4], ss[4];
    #pragma unroll
    for (int k = 0; k < 4; ++k) {
        const int j = jbase + 16 * k;
        const float4 pj4 = *(const float4*)(proj + (size_t)(b * N_FIXED + j) * 128 + 64 + p0);
        v[k].x = pi4.x + pj4.x;
        v[k].y = pi4.y + pj4.y;
        v[k].z = pi4.z + pj4.z;
        v[k].w = pi4.w + pj4.w;
        s[k]  = v[k].x + v[k].y + v[k].z + v[k].w;
        ss[k] = v[k].x * v[k].x + v[k].y * v[k].y + v[k].z * v[k].z + v[k].w * v[k].w;
    }

    #pragma unroll
    for (int mask = 1; mask < 16; mask <<= 1) {
        #pragma unroll
        for (int k = 0; k < 4; ++k) {
            s[k]  += __shfl_xor(s[k],  mask, 64);
            ss[k] += __shfl_xor(ss[k], mask, 64);
        }
    }

    #pragma unroll
    for (int k = 0; k < 4; ++k) {
        const int j = jbase + 16 * k;
        const float mean = s[k] * (1.f / PAIR_DIM);
        const float var  = ss[k] * (1.f / PAIR_DIM) - mean * mean;
        const float rstd = rsqrtf(var + LN_EPS);

        int rel = j - i;
        rel = (rel < -MAX_REL) ? -MAX_REL : (rel > MAX_REL ? MAX_REL : rel);
        rel += MAX_REL;
        const float4 e4 = *(const float4*)(embed + rel * PAIR_DIM + p0);

        vfloat4 o;
        o.x = fmaxf((v[k].x - mean) * rstd * g4.x + b4.x, 0.f) + e4.x;
        o.y = fmaxf((v[k].y - mean) * rstd * g4.y + b4.y, 0.f) + e4.y;
        o.z = fmaxf((v[k].z - mean) * rstd * g4.z + b4.z, 0.f) + e4.z;
        o.w = fmaxf((v[k].w - mean) * rstd * g4.w + b4.w, 0.f) + e4.w;

        __builtin_nontemporal_store(o,
            (vfloat4*)(out + ((size_t)bi * N_FIXED + j) * PAIR_DIM + p0));
    }
}

extern "C" void kernel_launch(void* const* d_in, const int* in_sizes, int n_in,
                              void* d_out, int out_size, void* d_ws, size_t ws_size,
                              hipStream_t stream) {
    const float* s     = (const float*)d_in[0];   // (B, N, 256)
    const float* W     = (const float*)d_in[1];   // (512, 64)
    const float* bias  = (const float*)d_in[2];   // (64,)
    const float* gamma = (const float*)d_in[3];   // (64,)
    const float* beta  = (const float*)d_in[4];   // (64,)
    const float* embed = (const float*)d_in[5];   // (65, 64)
    float* out  = (float*)d_out;

    const int BN = in_sizes[0] / SINGLE_DIM;      // B*N = 2048
    const int B  = BN / N_FIXED;

    // workspace layout
    const size_t off_proj = 0;
    const size_t sz_proj  = (size_t)BN * 128 * sizeof(float);          // 1 MB
    const size_t off_rs   = off_proj + sz_proj;
    const size_t sz_rs    = (size_t)BN * 4 * sizeof(float);            // 32 KB
    const size_t off_M    = off_rs + sz_rs;
    const size_t sz_M     = (size_t)BN * N_FIXED * sizeof(float2);     // 16.8 MB
    const size_t need     = off_M + sz_M;

    float*  proj     = (float*)((char*)d_ws + off_proj);
    float*  rowstats = (float*)((char*)d_ws + off_rs);
    float2* M        = (float2*)((char*)d_ws + off_M);

    const int pair_blocks = BN * (N_FIXED / 64);  // 32768

    if (ws_size >= need) {
        proj_kernel<<<BN / 2, 256, 0, stream>>>(s, W, bias, proj, rowstats);
        stats_kernel<<<B * 16 * 16, 256, 0, stream>>>(proj, rowstats, M);
        pair_fast_kernel<<<pair_blocks, 256, 0, stream>>>(proj, M, gamma, beta, embed, out);
    } else {
        proj_kernel<<<BN / 2, 256, 0, stream>>>(s, W, bias, proj, nullptr);
        pair_kernel<<<pair_blocks, 256, 0, stream>>>(proj, gamma, beta, embed, out);
    }
}